// Round 22
// baseline (158.112 us; speedup 1.0000x reference)
//
#include <hip/hip_runtime.h>
#include <hip/hip_bf16.h>

typedef __bf16 bf16;
typedef __attribute__((ext_vector_type(8))) __bf16 bf16x8;
typedef __attribute__((ext_vector_type(2))) __bf16 bf16x2;
typedef __attribute__((ext_vector_type(4))) float f32x4;
typedef __attribute__((ext_vector_type(4))) unsigned int uint4v;

#define C_NODES 63
#define F_DIM   250
#define CF      (C_NODES * F_DIM)
#define NEG_SLOPE 0.2f
#define NP 8               // batch PAIRS per block; grid 256 -> 4096 batches

// LDS map (148480 B -> 1 block/CU):
//   [0, 131040)       SLAB: X f32 for a batch PAIR, 126 rows x 1040 B.
//                     Row r<63 = batch0 row r; row 63+r = batch1 row r.
//                     DMA fills [0,992); tail 248/249 at [992,1000);
//                     zeros [1000,1024) set once.
//   [131072, 147456)  ALPHA: 2 x alpha[64][64] bf16 (swz, 128 B rows)
//   [147456, 148480)  AS0[64] | AD0[64] | AS1[64] | AD1[64]  (f32)
#define ROWB      1040
#define SLAB      0
#define ALPHA_B   131072
#define OFF_AS    147456
#define OFF_AD    147712
#define LDS_BYTES 148480

__device__ __forceinline__ int swz(int a) { return a ^ ((a >> 3) & 0x70); }

typedef const __attribute__((address_space(1))) void* gas_t;
typedef __attribute__((address_space(3))) void* las_t;
__device__ __forceinline__ void dma16(const void* g, void* l) {
    __builtin_amdgcn_global_load_lds((gas_t)g, (las_t)l, 16, 0, 0);
}

// lgkm-only barrier: DMA/stores (vmcnt) stay in flight across phases.
__device__ __forceinline__ void bar_lgkm() {
    asm volatile("s_waitcnt lgkmcnt(0)" ::: "memory");
    __builtin_amdgcn_s_barrier();
    __builtin_amdgcn_sched_barrier(0);
}

// Pack W (250x250 f32) into bf16 MFMA-B fragment order, padded to 256x256.
// Columns 250/251 hold ws = W@att_src and wd = W@att_dst, so GEMM1 emits the
// per-node scores a_s, a_d directly. Rows k>=250 are zero (kills A-garbage).
extern "C" __global__ __launch_bounds__(256)
void gat_prep(const float* __restrict__ W, const float* __restrict__ att_src,
              const float* __restrict__ att_dst, bf16* __restrict__ Wp) {
    int i = blockIdx.x * 256 + threadIdx.x;   // 0..65535
    int tile = i >> 9;
    int ln   = (i >> 3) & 63;
    int j    = i & 7;
    int kt = tile >> 4, nt = tile & 15;
    int k = kt * 32 + (ln >> 4) * 8 + j;
    int n = nt * 16 + (ln & 15);
    float v = 0.f;
    if (k < F_DIM) {
        if (n < F_DIM) {
            v = W[k * F_DIM + n];
        } else if (n == F_DIM || n == F_DIM + 1) {
            const float* att = (n == F_DIM) ? att_src : att_dst;
            float s = 0.f;
            for (int o = 0; o < F_DIM; ++o) s = fmaf(W[k * F_DIM + o], att[o], s);
            v = s;
        }
    }
    Wp[i] = (bf16)v;
}

// 512 threads = 8 waves; wave w owns output cols [w*32, w*32+32).
// Persistent: NP batch-pairs per block; per pair phases A|B|D with 3
// lgkm-only barriers (= 1.5 barriers/batch). GEMM1 does a fused 126-row
// M-tile so the 16 Wp L2 loads/wave amortize over 2 batches.
extern "C" __global__ __launch_bounds__(512, 2)
void gat_main(const float* __restrict__ x, const bf16* __restrict__ Wp,
              const float* __restrict__ bias, float* __restrict__ out)
{
    __shared__ __align__(16) unsigned char smem[LDS_BYTES];
    const int tid  = threadIdx.x;
    const int lane = tid & 63;
    const int w    = tid >> 6;        // wave id 0..7
    const int fl   = lane & 15;
    const int fh   = lane >> 4;
    const int b0   = blockIdx.x * (2 * NP);

    const bf16x8* wpv = (const bf16x8*)Wp;

    float bv0, bv1;
    { int f = w * 32 + fl;      bv0 = (f < F_DIM) ? bias[f] : 0.f;
      f += 16;                  bv1 = (f < F_DIM) ? bias[f] : 0.f; }

    // one-time: zero slab cols 250-255 of all 126 rows
    if (tid < 126) {
        *(unsigned long long*)(smem + SLAB + tid * ROWB + 1000) = 0ull;
        *(f32x4*)(smem + SLAB + tid * ROWB + 1008) = (f32x4){0.f, 0.f, 0.f, 0.f};
    }

    // prime pair 0: DMA 126 rows + reg tails
    {
        const float* xa = x + (size_t)b0 * CF;
        const float* xb2 = x + (size_t)(b0 + 1) * CF;
        float2 tl0 = {0.f, 0.f};
        if (tid < 126) {
            const float* s = (tid < 63) ? (xa + tid * F_DIM)
                                        : (xb2 + (tid - 63) * F_DIM);
            tl0 = *(const float2*)(s + 248);
        }
#pragma unroll
        for (int rr = 0; rr < 16; ++rr) {
            int r = w * 16 + rr;
            if (r < 126 && lane < 62) {
                const float* s = (r < 63) ? (xa + r * F_DIM)
                                          : (xb2 + (r - 63) * F_DIM);
                dma16(s + lane * 4, smem + SLAB + r * ROWB);
            }
        }
        if (tid < 126) *(float2*)(smem + SLAB + tid * ROWB + 992) = tl0;
    }
    asm volatile("s_waitcnt vmcnt(0)" ::: "memory");
    __syncthreads();   // slab(pair 0) visible

#pragma unroll 1
    for (int j = 0; j < NP; ++j) {
        const int b = b0 + 2 * j;
        const bool pfen = (j + 1 < NP);

        // ---- A: fused GEMM1 (126 rows, mt 0-3 = batch0, 4-7 = batch1);
        //         AS/AD extract (w7) for both batches; bar1 ----
        f32x4 gacc[8][2];
#pragma unroll
        for (int mt = 0; mt < 8; ++mt) {
            gacc[mt][0] = (f32x4){0.f, 0.f, 0.f, 0.f};
            gacc[mt][1] = (f32x4){0.f, 0.f, 0.f, 0.f};
        }
#pragma unroll 2
        for (int kt = 0; kt < 8; ++kt) {
            bf16x8 bw0 = wpv[(kt * 16 + w * 2)     * 64 + lane];
            bf16x8 bw1 = wpv[(kt * 16 + w * 2 + 1) * 64 + lane];
#pragma unroll
            for (int mt = 0; mt < 8; ++mt) {
                int lr = (mt & 3) * 16 + fl;           // row within batch
                int sr = lr + (mt >> 2) * 63;          // slab row
                bf16x8 af;
                if (lr < C_NODES) {
                    const f32x4* p = (const f32x4*)(smem + SLAB + sr * ROWB + kt * 128 + fh * 32);
                    f32x4 lo = p[0], hi = p[1];
                    af = (bf16x8){ (bf16)lo.x, (bf16)lo.y, (bf16)lo.z, (bf16)lo.w,
                                   (bf16)hi.x, (bf16)hi.y, (bf16)hi.z, (bf16)hi.w };
                } else {
                    af = (bf16x8){(bf16)0.f,(bf16)0.f,(bf16)0.f,(bf16)0.f,
                                  (bf16)0.f,(bf16)0.f,(bf16)0.f,(bf16)0.f};
                }
                gacc[mt][0] = __builtin_amdgcn_mfma_f32_16x16x32_bf16(af, bw0, gacc[mt][0], 0, 0, 0);
                gacc[mt][1] = __builtin_amdgcn_mfma_f32_16x16x32_bf16(af, bw1, gacc[mt][1], 0, 0, 0);
            }
        }
        if (w == 7 && (fl == 10 || fl == 11)) {      // cols 250 / 251
#pragma unroll
            for (int mt = 0; mt < 8; ++mt) {
                float* dst = (float*)(smem + (fl == 10 ? OFF_AS : OFF_AD) + (mt >> 2) * 512);
                f32x4 v = gacc[mt][1];
#pragma unroll
                for (int q = 0; q < 4; ++q)
                    dst[(mt & 3) * 16 + fh * 4 + q] = v[q];
            }
        }
        bar_lgkm();   // bar1: slab reads + AS/AD writes done

        // ---- B: DMA(next pair); H transpose (both batches); softmax
        //         (both batches); tail write; bar2 ----
        float2 tl = {0.f, 0.f};
        if (pfen) {
            const float* xa = x + (size_t)(b + 2) * CF;
            const float* xb2 = x + (size_t)(b + 3) * CF;
            if (tid < 126) {
                const float* s = (tid < 63) ? (xa + tid * F_DIM)
                                            : (xb2 + (tid - 63) * F_DIM);
                tl = *(const float2*)(s + 248);
            }
#pragma unroll
            for (int rr = 0; rr < 16; ++rr) {
                int r = w * 16 + rr;
                if (r < 126 && lane < 62) {
                    const float* s = (r < 63) ? (xa + r * F_DIM)
                                              : (xb2 + (r - 63) * F_DIM);
                    dma16(s + lane * 4, smem + SLAB + r * ROWB);
                }
            }
        }
        // in-register H transpose, per batch h
        const int LA = ((fh & 1) << 5) + fl;
        const int LB = LA + 16;
        const bool fhHi = (fh & 2) != 0;
        uint4v hb[2][2][2];   // [h][nti][kt2]
#pragma unroll
        for (int h = 0; h < 2; ++h) {
            unsigned int pk[4][2][2];
#pragma unroll
            for (int mt4 = 0; mt4 < 4; ++mt4)
#pragma unroll
                for (int nti = 0; nti < 2; ++nti) {
                    f32x4 v = gacc[h * 4 + mt4][nti];
                    bf16x2 p0 = { (bf16)v.x, (bf16)v.y };
                    bf16x2 p1 = { (bf16)v.z, (bf16)v.w };
                    pk[mt4][nti][0] = __builtin_bit_cast(unsigned int, p0);
                    pk[mt4][nti][1] = __builtin_bit_cast(unsigned int, p1);
                }
#pragma unroll
            for (int nti = 0; nti < 2; ++nti)
#pragma unroll
                for (int kt2 = 0; kt2 < 2; ++kt2) {
                    unsigned int u[4];
#pragma unroll
                    for (int hh = 0; hh < 2; ++hh) {
                        unsigned int a0 = __shfl(pk[kt2 * 2][nti][hh],     LA);
                        unsigned int a1 = __shfl(pk[kt2 * 2 + 1][nti][hh], LA);
                        u[hh] = fhHi ? a1 : a0;
                        unsigned int c0 = __shfl(pk[kt2 * 2][nti][hh],     LB);
                        unsigned int c1 = __shfl(pk[kt2 * 2 + 1][nti][hh], LB);
                        u[2 + hh] = fhHi ? c1 : c0;
                    }
                    hb[h][nti][kt2] = (uint4v){u[0], u[1], u[2], u[3]};
                }
        }
        // softmax, both batches at once: half=tid>>8, d=(tid>>2)&63, c=tid&3
        {
            int half = tid >> 8;
            int d    = (tid >> 2) & 63;
            int c    = tid & 3;
            const float* AS  = (const float*)(smem + OFF_AS + half * 512);
            const float* ADp = (const float*)(smem + OFF_AD + half * 512);
            float ad_v = ADp[d];
            f32x4 s0 = *(const f32x4*)(AS + c * 16);
            f32x4 s1 = *(const f32x4*)(AS + c * 16 + 4);
            f32x4 s2 = *(const f32x4*)(AS + c * 16 + 8);
            f32x4 s3 = *(const f32x4*)(AS + c * 16 + 12);
            float p[16];
#pragma unroll
            for (int k = 0; k < 4; ++k) {
                float e;
                e = s0[k] + ad_v; p[k]      = (e > 0.f) ? e : NEG_SLOPE * e;
                e = s1[k] + ad_v; p[4 + k]  = (e > 0.f) ? e : NEG_SLOPE * e;
                e = s2[k] + ad_v; p[8 + k]  = (e > 0.f) ? e : NEG_SLOPE * e;
                e = s3[k] + ad_v; p[12 + k] = (e > 0.f) ? e : NEG_SLOPE * e;
            }
            if (c == 3) p[15] = -3.0e38f;   // s=63 excluded (63 sources)
            float md = p[0];
#pragma unroll
            for (int k = 1; k < 16; ++k) md = fmaxf(md, p[k]);
            md = fmaxf(md, __shfl_xor(md, 1));
            md = fmaxf(md, __shfl_xor(md, 2));
            float sum = 0.f;
#pragma unroll
            for (int k = 0; k < 16; ++k) { p[k] = __expf(p[k] - md); sum += p[k]; }
            sum += __shfl_xor(sum, 1);
            sum += __shfl_xor(sum, 2);
            float rz = 1.f / sum;
            bf16x8 pk0, pk1;
#pragma unroll
            for (int k = 0; k < 8; ++k) {
                pk0[k] = (bf16)(p[k] * rz);
                pk1[k] = (bf16)(p[8 + k] * rz);
            }
            int base = ALPHA_B + half * 8192 + d * 128 + c * 32;
            *(bf16x8*)(smem + swz(base))      = pk0;
            *(bf16x8*)(smem + swz(base + 16)) = pk1;
        }
        if (pfen && tid < 126)
            *(float2*)(smem + SLAB + tid * ROWB + 992) = tl;
        bar_lgkm();   // bar2: alpha + slab tail visible (DMA flying)

        // ---- D: GEMM2 both batches (gacc reused); stores; vmcnt(63); bar3 --
#pragma unroll
        for (int mt = 0; mt < 8; ++mt) {
            gacc[mt][0] = (f32x4){0.f, 0.f, 0.f, 0.f};
            gacc[mt][1] = (f32x4){0.f, 0.f, 0.f, 0.f};
        }
#pragma unroll
        for (int h = 0; h < 2; ++h)
#pragma unroll
            for (int ks = 0; ks < 2; ++ks) {
                int kk = ks * 32 + fh * 8;
                bf16x8 h0 = __builtin_bit_cast(bf16x8, hb[h][0][ks]);
                bf16x8 h1 = __builtin_bit_cast(bf16x8, hb[h][1][ks]);
#pragma unroll
                for (int mt4 = 0; mt4 < 4; ++mt4) {
                    bf16x8 aal = *(const bf16x8*)(smem + swz(ALPHA_B + h * 8192
                                        + (mt4 * 16 + fl) * 128 + kk * 2));
                    gacc[h * 4 + mt4][0] = __builtin_amdgcn_mfma_f32_16x16x32_bf16(aal, h0, gacc[h * 4 + mt4][0], 0, 0, 0);
                    gacc[h * 4 + mt4][1] = __builtin_amdgcn_mfma_f32_16x16x32_bf16(aal, h1, gacc[h * 4 + mt4][1], 0, 0, 0);
                }
            }
#pragma unroll
        for (int h = 0; h < 2; ++h) {
            float* ob = out + (size_t)(b + h) * CF;
#pragma unroll
            for (int mt4 = 0; mt4 < 4; ++mt4) {
#pragma unroll
                for (int q = 0; q < 4; ++q) {
                    int r = mt4 * 16 + fh * 4 + q;
                    if (r < C_NODES) {
                        int f = w * 32 + fl;
                        ob[r * F_DIM + f] = gacc[h * 4 + mt4][0][q] + bv0;
                        f += 16;
                        if (f < F_DIM) ob[r * F_DIM + f] = gacc[h * 4 + mt4][1][q] + bv1;
                    }
                }
            }
        }
        if (pfen) {
            // <=16 DMAs (oldest) + 64 stores (youngest) in flight; vmcnt max
            // is 63 on gfx9. vmcnt(63) in-order retires the oldest >=17 ops
            // == all DMAs landed, stores keep flying.
            asm volatile("s_waitcnt vmcnt(63)" ::: "memory");
        }
        bar_lgkm();   // bar3: slab(next pair) + alpha reads drained
    }
}

extern "C" void kernel_launch(void* const* d_in, const int* in_sizes, int n_in,
                              void* d_out, int out_size, void* d_ws, size_t ws_size,
                              hipStream_t stream) {
    const float* x       = (const float*)d_in[0];
    const float* W       = (const float*)d_in[1];
    const float* att_src = (const float*)d_in[2];
    const float* att_dst = (const float*)d_in[3];
    const float* bias    = (const float*)d_in[4];
    float* out = (float*)d_out;
    bf16* Wp = (bf16*)d_ws;   // 65536 bf16 = 128 KB packed W (+score cols)

    gat_prep<<<256, 256, 0, stream>>>(W, att_src, att_dst, Wp);
    gat_main<<<256, 512, 0, stream>>>(x, Wp, bias, out);
}

// Round 23
// 133.673 us; speedup vs baseline: 1.1828x; 1.1828x over previous
//
#include <hip/hip_runtime.h>
#include <hip/hip_bf16.h>

typedef __bf16 bf16;
typedef __attribute__((ext_vector_type(8))) __bf16 bf16x8;
typedef __attribute__((ext_vector_type(4))) __bf16 bf16x4;
typedef __attribute__((ext_vector_type(2))) __bf16 bf16x2;
typedef __attribute__((ext_vector_type(4))) float f32x4;

#define C_NODES 63
#define F_DIM   250
#define NEG_SLOPE 0.2f
#define BS 16              // batches per persistent block; grid 256 = 1/CU

// LDS map (139264 B -> 1 block/CU):
//   [0, 65520)        SLAB: X f32, 63 rows x 1040 B. DMA fills [0,992) per
//                     row; tail 248/249 reg-staged at [992,1000);
//                     zeros [1000,1024) (cols 250-255, set once).
//   [65536, 98304)    AFR: bf16 MFMA A-frags (swzA). Fully rewritten by the
//                     conversion pass each batch except row 63 (guarded once).
//   [98304, 130304)   HSB: Hs[f][s] bf16, f<250 (swz row-local)
//   [130304, 130560)  AS: a_s[64] f32
//   [130560, 130816)  AD: a_d[64] f32
//   [131072, 139264)  ALPHA: alpha[64][64] bf16 (swz, 128 B rows)
#define ROWB      1040
#define SLAB      0
#define AFR_B     65536
#define HSB       98304
#define OFF_AS    130304
#define OFF_AD    130560
#define ALPHA_B   131072
#define LDS_BYTES 139264

__device__ __forceinline__ int swz(int a) { return a ^ ((a >> 3) & 0x70); }
// A-frag swizzle (local offset within AFR): bank-spread writes/reads.
__device__ __forceinline__ int swzA(int a) {
    return a ^ ((((a >> 8) & 3) ^ ((a >> 10) & 3)) << 4) ^ (((a >> 12) & 1) << 6);
}

typedef const __attribute__((address_space(1))) void* gas_t;
typedef __attribute__((address_space(3))) void* las_t;
__device__ __forceinline__ void dma16(const void* g, void* l) {
    __builtin_amdgcn_global_load_lds((gas_t)g, (las_t)l, 16, 0, 0);
}

// lgkm-only barrier: DMA/stores (vmcnt) stay in flight across phases.
__device__ __forceinline__ void bar_lgkm() {
    asm volatile("s_waitcnt lgkmcnt(0)" ::: "memory");
    __builtin_amdgcn_s_barrier();
    __builtin_amdgcn_sched_barrier(0);
}

// Wave-local conversion: wave w converts its own DMA'd rows w*8..w*8+7 from
// f32 slab to bf16 A-fragments. Lane covers cols lane*4..lane*4+3 (lane 62
// picks up tail 248/249 + zeros 250/251, lane 63 the zero cols 252-255).
__device__ __forceinline__ void conv_rows(unsigned char* smem, int w, int lane) {
#pragma unroll
    for (int rr = 0; rr < 8; ++rr) {
        int r = w * 8 + rr;
        if (r < C_NODES) {     // uniform per wave: wave 7 skips rr=7
            f32x4 v = *(const f32x4*)(smem + SLAB + r * ROWB + lane * 16);
            int c = lane * 4;
            int dl = (r & 15) | (((c >> 3) & 3) << 4);
            int base = AFR_B + swzA((((r >> 4) * 8 + (c >> 5)) << 10)
                                    + dl * 16 + (c & 4) * 2);
            bf16x4 o = { (bf16)v.x, (bf16)v.y, (bf16)v.z, (bf16)v.w };
            *(bf16x4*)(smem + base) = o;
        }
    }
}

// Pack W (250x250 f32) into bf16 MFMA-B fragment order, padded to 256x256.
// Columns 250/251 hold ws = W@att_src and wd = W@att_dst, so GEMM1 emits the
// per-node scores a_s, a_d directly. Rows k>=250 are zero (kills A-garbage).
extern "C" __global__ __launch_bounds__(256)
void gat_prep(const float* __restrict__ W, const float* __restrict__ att_src,
              const float* __restrict__ att_dst, bf16* __restrict__ Wp) {
    int i = blockIdx.x * 256 + threadIdx.x;   // 0..65535
    int tile = i >> 9;
    int ln   = (i >> 3) & 63;
    int j    = i & 7;
    int kt = tile >> 4, nt = tile & 15;
    int k = kt * 32 + (ln >> 4) * 8 + j;
    int n = nt * 16 + (ln & 15);
    float v = 0.f;
    if (k < F_DIM) {
        if (n < F_DIM) {
            v = W[k * F_DIM + n];
        } else if (n == F_DIM || n == F_DIM + 1) {
            const float* att = (n == F_DIM) ? att_src : att_dst;
            float s = 0.f;
            for (int o = 0; o < F_DIM; ++o) s = fmaf(W[k * F_DIM + o], att[o], s);
            v = s;
        }
    }
    Wp[i] = (bf16)v;
}

// 512 threads = 8 waves; wave w owns output cols [w*32, w*32+32).
// Persistent BS=16; phases A|B|D, 3 lgkm-only barriers; DMA f32 slab ->
// wave-local bf16 conversion -> half the GEMM1 LDS reads; Hs via LDS
// (cheaper on the DS pipe than the shuffle transpose).
extern "C" __global__ __launch_bounds__(512, 2)
void gat_main(const float* __restrict__ x, const bf16* __restrict__ Wp,
              const float* __restrict__ bias, float* __restrict__ out)
{
    __shared__ __align__(16) unsigned char smem[LDS_BYTES];
    const int tid  = threadIdx.x;
    const int lane = tid & 63;
    const int w    = tid >> 6;        // wave id 0..7
    const int fl   = lane & 15;
    const int fh   = lane >> 4;
    const int b0   = blockIdx.x * BS;

    const bf16x8* wpv = (const bf16x8*)Wp;

    float bv0, bv1;
    { int f = w * 32 + fl;      bv0 = (f < F_DIM) ? bias[f] : 0.f;
      f += 16;                  bv1 = (f < F_DIM) ? bias[f] : 0.f; }

    // one-time guards: slab zero cols 250-255; AFR row-63 slots (conv never
    // writes row 63; everything else is rewritten every batch).
    if (tid < 63) {
        *(unsigned long long*)(smem + SLAB + tid * ROWB + 1000) = 0ull;
        *(f32x4*)(smem + SLAB + tid * ROWB + 1008) = (f32x4){0.f, 0.f, 0.f, 0.f};
    } else if (tid < 96) {
        int idx = tid - 64;
        int base = AFR_B + swzA(((24 + (idx >> 2)) << 10) + ((((idx & 3) << 4) | 15) * 16));
        *(f32x4*)(smem + base) = (f32x4){0.f, 0.f, 0.f, 0.f};
    }

    // prime: stage slab(b0) via DMA + reg tail, then convert to AFR
    {
        const float* xb = x + (size_t)b0 * (C_NODES * F_DIM);
        float2 tl0 = {0.f, 0.f};
        if (tid < 63) tl0 = *(const float2*)(xb + tid * F_DIM + 248);
#pragma unroll
        for (int rr = 0; rr < 8; ++rr) {
            int r = w * 8 + rr;
            if (r < 63 && lane < 62)
                dma16(xb + r * F_DIM + lane * 4, smem + SLAB + r * ROWB);
        }
        if (tid < 63) *(float2*)(smem + SLAB + tid * ROWB + 992) = tl0;
    }
    asm volatile("s_waitcnt vmcnt(0)" ::: "memory");
    __syncthreads();           // slab(b0) fully visible (incl. tail by wave 0)
    conv_rows(smem, w, lane);
    bar_lgkm();                // AFR(b0) visible

#pragma unroll 1
    for (int i = 0; i < BS; ++i) {
        const int b = b0 + i;
        const bool pfen = (i + 1 < BS);
        const float* xnext = x + (size_t)(b + 1) * (C_NODES * F_DIM);

        // ---- A: GEMM1 from AFR (bf16); AS/AD extract (w7); bar1 ----
        f32x4 gacc[4][2];
#pragma unroll
        for (int mt = 0; mt < 4; ++mt) {
            gacc[mt][0] = (f32x4){0.f, 0.f, 0.f, 0.f};
            gacc[mt][1] = (f32x4){0.f, 0.f, 0.f, 0.f};
        }
#pragma unroll 2
        for (int kt = 0; kt < 8; ++kt) {
            bf16x8 bw0 = wpv[(kt * 16 + w * 2)     * 64 + lane];
            bf16x8 bw1 = wpv[(kt * 16 + w * 2 + 1) * 64 + lane];
#pragma unroll
            for (int mt = 0; mt < 4; ++mt) {
                bf16x8 af = *(const bf16x8*)(smem + AFR_B
                                + swzA(((mt * 8 + kt) << 10) + lane * 16));
                gacc[mt][0] = __builtin_amdgcn_mfma_f32_16x16x32_bf16(af, bw0, gacc[mt][0], 0, 0, 0);
                gacc[mt][1] = __builtin_amdgcn_mfma_f32_16x16x32_bf16(af, bw1, gacc[mt][1], 0, 0, 0);
            }
        }
        if (w == 7 && (fl == 10 || fl == 11)) {      // cols 250 / 251
            float* dst = (float*)(smem + (fl == 10 ? OFF_AS : OFF_AD));
#pragma unroll
            for (int mt = 0; mt < 4; ++mt) {
                f32x4 v = gacc[mt][1];
#pragma unroll
                for (int q = 0; q < 4; ++q) dst[mt * 16 + fh * 4 + q] = v[q];
            }
        }
        bar_lgkm();   // bar1: AFR reads + AS/AD writes done

        // ---- B: tl(i+1) load; DMA(i+1) -> slab; Hs write; softmax;
        //         tl write; bar2 ----
        float2 tl = {0.f, 0.f};
        if (pfen) {
            if (tid < 63) tl = *(const float2*)(xnext + tid * F_DIM + 248);
#pragma unroll
            for (int rr = 0; rr < 8; ++rr) {
                int r = w * 8 + rr;
                if (r < 63 && lane < 62)
                    dma16(xnext + r * F_DIM + lane * 4, smem + SLAB + r * ROWB);
            }
        }
        // Hs[f][s] bf16 (swz), f<250
#pragma unroll
        for (int mt = 0; mt < 4; ++mt) {
            int s0 = mt * 16 + fh * 4;
#pragma unroll
            for (int nti = 0; nti < 2; ++nti) {
                int f = w * 32 + nti * 16 + fl;
                if (f < F_DIM) {
                    f32x4 v = gacc[mt][nti];
                    bf16x4 hv = { (bf16)v.x, (bf16)v.y, (bf16)v.z, (bf16)v.w };
                    *(bf16x4*)(smem + swz(HSB + f * 128 + s0 * 2)) = hv;
                }
            }
        }
        // softmax (block-wide, once): thread=(d=tid>>3, c=tid&7)
        {
            const float* AS  = (const float*)(smem + OFF_AS);
            const float* ADp = (const float*)(smem + OFF_AD);
            int d = tid >> 3;
            int c = tid & 7;
            float ad_v = ADp[d];
            f32x4 a0 = *(const f32x4*)(AS + c * 8);
            f32x4 a1 = *(const f32x4*)(AS + c * 8 + 4);
            float p[8];
#pragma unroll
            for (int k = 0; k < 4; ++k) {
                float e;
                e = a0[k] + ad_v; p[k]     = (e > 0.f) ? e : NEG_SLOPE * e;
                e = a1[k] + ad_v; p[4 + k] = (e > 0.f) ? e : NEG_SLOPE * e;
            }
            if (c == 7) p[7] = -3.0e38f;   // s=63 excluded (63 sources)
            float md = p[0];
#pragma unroll
            for (int k = 1; k < 8; ++k) md = fmaxf(md, p[k]);
            md = fmaxf(md, __shfl_xor(md, 1));
            md = fmaxf(md, __shfl_xor(md, 2));
            md = fmaxf(md, __shfl_xor(md, 4));
            float sum = 0.f;
#pragma unroll
            for (int k = 0; k < 8; ++k) { p[k] = __expf(p[k] - md); sum += p[k]; }
            sum += __shfl_xor(sum, 1);
            sum += __shfl_xor(sum, 2);
            sum += __shfl_xor(sum, 4);
            float rz = 1.f / sum;
            bf16x8 pkv;
#pragma unroll
            for (int k = 0; k < 8; ++k) pkv[k] = (bf16)(p[k] * rz);
            *(bf16x8*)(smem + swz(ALPHA_B + d * 128 + c * 16)) = pkv;
        }
        if (pfen && tid < 63)
            *(float2*)(smem + SLAB + tid * ROWB + 992) = tl;
        bar_lgkm();   // bar2: Hs + alpha + slab-tail visible (DMA flying)

        // ---- D: GEMM2 (Hs + alpha); stores; vmcnt(32); conv(i+1); bar3 ----
#pragma unroll
        for (int mt = 0; mt < 4; ++mt) {
            gacc[mt][0] = (f32x4){0.f, 0.f, 0.f, 0.f};
            gacc[mt][1] = (f32x4){0.f, 0.f, 0.f, 0.f};
        }
#pragma unroll
        for (int ks = 0; ks < 2; ++ks) {
            int kk = ks * 32 + fh * 8;
            bf16x8 hbf0 = *(const bf16x8*)(smem + swz(HSB + (w * 32 + fl)      * 128 + kk * 2));
            bf16x8 hbf1 = *(const bf16x8*)(smem + swz(HSB + (w * 32 + fl + 16) * 128 + kk * 2));
#pragma unroll
            for (int mt = 0; mt < 4; ++mt) {
                bf16x8 aal = *(const bf16x8*)(smem + swz(ALPHA_B + (mt * 16 + fl) * 128 + kk * 2));
                gacc[mt][0] = __builtin_amdgcn_mfma_f32_16x16x32_bf16(aal, hbf0, gacc[mt][0], 0, 0, 0);
                gacc[mt][1] = __builtin_amdgcn_mfma_f32_16x16x32_bf16(aal, hbf1, gacc[mt][1], 0, 0, 0);
            }
        }
        float* ob = out + (size_t)b * (C_NODES * F_DIM);
#pragma unroll
        for (int mt = 0; mt < 4; ++mt) {
#pragma unroll
            for (int q = 0; q < 4; ++q) {
                int r = mt * 16 + fh * 4 + q;
                if (r < C_NODES) {
                    int f = w * 32 + fl;
                    ob[r * F_DIM + f] = gacc[mt][0][q] + bv0;
                    f += 16;
                    if (f < F_DIM) ob[r * F_DIM + f] = gacc[mt][1][q] + bv1;
                }
            }
        }
        if (pfen) {
            // 8 DMA ops are OLDER than the 32 stores just issued: vmcnt(32)
            // == "all DMA landed, stores may keep flying".
            asm volatile("s_waitcnt vmcnt(32)" ::: "memory");
            conv_rows(smem, w, lane);   // wave-local: own DMA rows + wave-0
                                        // tail crossed bar2
        }
        bar_lgkm();   // bar3: AFR(i+1) visible; alpha/Hs reads drained
    }
}

extern "C" void kernel_launch(void* const* d_in, const int* in_sizes, int n_in,
                              void* d_out, int out_size, void* d_ws, size_t ws_size,
                              hipStream_t stream) {
    const float* x       = (const float*)d_in[0];
    const float* W       = (const float*)d_in[1];
    const float* att_src = (const float*)d_in[2];
    const float* att_dst = (const float*)d_in[3];
    const float* bias    = (const float*)d_in[4];
    float* out = (float*)d_out;
    bf16* Wp = (bf16*)d_ws;   // 65536 bf16 = 128 KB packed W (+score cols)

    gat_prep<<<256, 256, 0, stream>>>(W, att_src, att_dst, Wp);
    gat_main<<<256, 512, 0, stream>>>(x, Wp, bias, out);
}